// Round 7
// baseline (833.260 us; speedup 1.0000x reference)
//
#include <hip/hip_runtime.h>
#include <hip/hip_bf16.h>

typedef __attribute__((ext_vector_type(4))) float float4v;
typedef __attribute__((ext_vector_type(8))) __bf16 bf16x8;
typedef __attribute__((ext_vector_type(8))) unsigned short ushort8v;

constexpr int NTOK = 50176;
constexpr int DIM  = 384;
constexpr int HID  = 1536;
constexpr int BM   = 64;          // tokens per block (was 128) -> 56KB LDS -> 2 blocks/CU
constexpr int NTH  = 512;
constexpr int NBLK = NTOK / BM;   // 784
constexpr int NCH  = 24;          // hidden chunks of 64

// workspace (byte offsets) — pre-swizzled bf16 images (byte-identical to R2-R6, proven)
constexpr int IMG_WD  = 0;                  // [32][384] 768B rows, 24576 B (WUP contiguous after)
constexpr int IMG_WUP = 24576;              // [384][32] 64B rows,  24576 B
constexpr int IMG_W1  = 49152;              // 24 x [64][384] 768B rows, 49152 B each
constexpr int IMG_W2  = 49152 + 24*49152;   // 24 x [384][64] 128B rows
constexpr size_t WS_NEED = 2408448;
constexpr int NELEMS = 1204224;

// LDS byte offsets — 56 KiB total => 2 blocks/CU
constexpr int L_W  = 0;        // 48K  single W buffer (X-prologue temp / WD+WUP / W1 / W2)
constexpr int L_HS = 49152;    // 8K   Hs [64][64] bf16, 128B rows, swizzled
constexpr int LDSZ = 57344;

__device__ __forceinline__ unsigned short f2bf(float f) {
  __hip_bfloat16 h = __float2bfloat16(f);
  return *reinterpret_cast<unsigned short*>(&h);
}

__device__ __forceinline__ float gelu_f(float v) {
  float u = 0.7978845608f * (v + 0.044715f * v * v * v);
  float e = __expf(2.0f * u);
  float t = 1.0f - 2.0f / (e + 1.0f);
  return 0.5f * v * (1.0f + t);
}

// 48KB staging via NORMAL per-lane loads (L2-allocating; R4-proven 65MB FETCH).
// thread t, granule j <-> byte t*16 + j*8192 on both sides (pure linear copy).
__device__ __forceinline__ void stage_load(const char* src, int tid, ushort8v st[6]) {
  #pragma unroll
  for (int j = 0; j < 6; ++j)
    st[j] = *(const ushort8v*)(src + tid * 16 + j * 8192);
}
__device__ __forceinline__ void stage_write(char* dst, int tid, const ushort8v st[6]) {
  #pragma unroll
  for (int j = 0; j < 6; ++j)
    *(ushort8v*)(dst + tid * 16 + j * 8192) = st[j];
}

// ---------------- pack kernel: f32 weights -> pre-swizzled bf16 images (unchanged) ----------------
__global__ __launch_bounds__(256) void pack_k(
    const float* __restrict__ W1, const float* __restrict__ W2,
    const float* __restrict__ wd, const float* __restrict__ wu,
    unsigned short* __restrict__ img)
{
  int i = blockIdx.x * 256 + threadIdx.x;
  if (i >= NELEMS) return;
  if (i < 12288) {                              // WD: rows r=lora-col (0..31), 768B rows
    int r = i / 384; int inb = (i % 384) * 2;
    int d = (inb ^ ((r & 7) << 4)) >> 1;
    float f = (r < 24) ? wd[(r >> 3) * (DIM * 8) + d * 8 + (r & 7)] : 0.f;
    img[i] = f2bf(f);
  } else if (i < 24576) {                       // WUP: [384 d][32 k], 64B rows, cross-row swz
    int j = i - 12288; int a = j * 2;
    int dh = a >> 7; int b6 = (a >> 6) & 1;
    int d = dh * 2 + (b6 ^ ((dh >> 1) & 1));
    int k = ((a & 63) ^ ((d & 3) << 4)) >> 1;
    float f = (k < 24) ? wu[k * DIM + d] : 0.f;
    img[i] = f2bf(f);
  } else if (i < 24576 + 589824) {              // W1 chunks: [64 F][384 d], 768B rows
    int j = i - 24576; int h = j / 24576; int jc = j % 24576;
    int r = jc / 384; int inb = (jc % 384) * 2;
    int d = (inb ^ ((r & 7) << 4)) >> 1;
    img[i] = f2bf(W1[d * HID + h * 64 + r]);
  } else {                                      // W2 chunks: [384 d][64 k], 128B rows
    int j = i - 24576 - 589824; int h = j / 24576; int jc = j % 24576;
    int dd = jc / 64; int inb = (jc % 64) * 2;
    int k2 = (inb ^ ((dd & 7) << 4)) >> 1;
    img[i] = f2bf(W2[(h * 64 + k2) * DIM + dd]);
  }
}

// ---------------- fused MLP + MoE-LoRA ----------------
__global__ __launch_bounds__(NTH, 4) void fused_k(
    const float* __restrict__ x,
    const float* __restrict__ tp,
    const int*   __restrict__ ti,
    const float* __restrict__ b1,
    const float* __restrict__ b2,
    const unsigned short* __restrict__ img,
    float* __restrict__ out)
{
  extern __shared__ char lds[];
  const int tid = threadIdx.x, wid = tid >> 6, lane = tid & 63;
  const int lrow = lane & 15, g4 = lane >> 4, lkb = g4 * 8;
  const int blockRow = blockIdx.x * BM;
  const char* imgc = (const char*)img;

  ushort8v st[6];   // 24 arch VGPRs; alternates WD+WUP / W1 / W2 roles

  // ---- prologue: issue WD+WUP (48K contiguous); X f32->bf16 -> L_W (temp, swizzled) ----
  stage_load(imgc + IMG_WD, tid, st);          // lands under X staging
  {
    const float* xb = x + (size_t)blockRow * DIM;
    #pragma unroll
    for (int it = 0; it < 6; ++it) {           // 64*384 elems / (512*8)
      int idx = it * NTH + tid;
      int row = idx / 48, c8 = idx % 48;
      float4v v0 = *(const float4v*)(xb + row * DIM + c8 * 8);
      float4v v1 = *(const float4v*)(xb + row * DIM + c8 * 8 + 4);
      ushort8v u;
      u[0]=f2bf(v0[0]); u[1]=f2bf(v0[1]); u[2]=f2bf(v0[2]); u[3]=f2bf(v0[3]);
      u[4]=f2bf(v1[0]); u[5]=f2bf(v1[1]); u[6]=f2bf(v1[2]); u[7]=f2bf(v1[3]);
      int byte = (row * 768 + c8 * 16) ^ ((row & 7) << 4);
      *(ushort8v*)(lds + L_W + byte) = u;
    }
  }
  __syncthreads();                             // X visible

  // ---- X A-fragments -> registers (48 VGPRs). G1 grid: 4 bands x 2 col-halves; 16 rows/wave ----
  const int band = wid >> 1, chh = wid & 1;
  bf16x8 xf[12];
  {
    int row = band * 16 + lrow;
    int rb = row * 768, sw = (row & 7) << 4;
    #pragma unroll
    for (int ks = 0; ks < 12; ++ks)
      xf[ks] = *(const bf16x8*)(lds + L_W + ((rb + (ks * 32 + lkb) * 2) ^ sw));
  }
  __syncthreads();                             // X reads done; L_W free

  stage_write(lds + L_W, tid, st);             // WD -> 0..24K, WUP -> 24..48K
  stage_load(imgc + IMG_W1, tid, st);          // W1[0]; lands under MoE compute
  __syncthreads();                             // WD/WUP visible

  // ---- G1-moe: t1 = X @ WdT -> [64][32] ----
  float4v h2 = {};
  {
    int rbw = chh * 16 + lrow, sww = (rbw & 7) << 4;
    #pragma unroll
    for (int ks = 0; ks < 12; ++ks) {
      bf16x8 b = *(const bf16x8*)(lds + L_W + ((rbw * 768 + (ks * 32 + lkb) * 2) ^ sww));
      h2 = __builtin_amdgcn_mfma_f32_16x16x32_bf16(xf[ks], b, h2, 0, 0, 0);
    }
  }
  // prob * gelu -> Hs cols 0..31
  {
    int col = chh * 16 + lrow; int e = col >> 3;
    #pragma unroll
    for (int r = 0; r < 4; ++r) {
      int row = band * 16 + g4 * 4 + r;
      int token = blockRow + row;
      float p = 0.f;
      if (e < 3) {
        int i0 = ti[token * 2], i1 = ti[token * 2 + 1];
        if (i0 == e) p += tp[token * 2];
        if (i1 == e) p += tp[token * 2 + 1];
      }
      float gv = p * gelu_f(h2[r]);
      int byte = (row * 128 + col * 2) ^ ((row & 7) << 4);
      *(unsigned short*)(lds + L_HS + byte) = f2bf(gv);
    }
  }
  __syncthreads();                             // Hs visible; WD reads done (WUP untouched)

  // ---- G2-moe: acc = Hs(0..31) @ WupT (K=32); WUP at L_W+24576 ----
  const int wr = wid >> 2, wc = wid & 3;       // G2 grid: 2M x 4N over [64][384]
  float4v acc[2][6] = {};
  {
    bf16x8 A[2];
    #pragma unroll
    for (int mt = 0; mt < 2; ++mt) {
      int ra = wr * 32 + mt * 16 + lrow;
      A[mt] = *(const bf16x8*)(lds + L_HS + ((ra * 128 + lkb * 2) ^ ((ra & 7) << 4)));
    }
    #pragma unroll
    for (int nt = 0; nt < 6; ++nt) {
      int rb = wc * 96 + nt * 16 + lrow;
      bf16x8 b = *(const bf16x8*)(lds + L_W + 24576 + ((rb * 64 + lkb * 2) ^ ((rb & 7) << 4)));
      #pragma unroll
      for (int mt = 0; mt < 2; ++mt)
        acc[mt][nt] = __builtin_amdgcn_mfma_f32_16x16x32_bf16(A[mt], b, acc[mt][nt], 0, 0, 0);
    }
  }

  // ---- main loop: R4's proven 4-barrier single-buffer timeline, reg staging ----
  for (int h = 0; h < NCH; ++h) {
    __syncthreads();                           // (a) L_W readers (G2-moe / G2[h-1]) done
    stage_write(lds + L_W, tid, st);           // W1[h] -> L_W (st landed long ago)
    __syncthreads();                           // (b) W1[h] visible
    stage_load(imgc + IMG_W2 + h * 49152, tid, st);   // W2[h]; lands under G1

    // G1: H = X @ W1c -> [64][64]; A from xf (no LDS A-reads)
    float4v hv[2] = {};
    {
      int rb0 = chh * 32 + lrow, rb1 = rb0 + 16;
      int t0 = (rb0 & 7) << 4, t1 = (rb1 & 7) << 4;
      #pragma unroll
      for (int ks = 0; ks < 12; ++ks) {
        int ko = (ks * 32 + lkb) * 2;
        bf16x8 b0 = *(const bf16x8*)(lds + L_W + ((rb0 * 768 + ko) ^ t0));
        bf16x8 b1v= *(const bf16x8*)(lds + L_W + ((rb1 * 768 + ko) ^ t1));
        hv[0] = __builtin_amdgcn_mfma_f32_16x16x32_bf16(xf[ks], b0,  hv[0], 0, 0, 0);
        hv[1] = __builtin_amdgcn_mfma_f32_16x16x32_bf16(xf[ks], b1v, hv[1], 0, 0, 0);
      }
    }
    // bias + gelu -> Hs
    #pragma unroll
    for (int nt = 0; nt < 2; ++nt) {
      int col = chh * 32 + nt * 16 + lrow;
      float bb = b1[h * 64 + col];
      #pragma unroll
      for (int r = 0; r < 4; ++r) {
        int row = band * 16 + g4 * 4 + r;
        float gv = gelu_f(hv[nt][r] + bb);
        int byte = (row * 128 + col * 2) ^ ((row & 7) << 4);
        *(unsigned short*)(lds + L_HS + byte) = f2bf(gv);
      }
    }
    __syncthreads();                           // (c) Hs visible; G1's L_W reads done
    stage_write(lds + L_W, tid, st);           // W2[h] -> L_W (waits vmcnt via st dep)
    __syncthreads();                           // (d) W2[h] visible
    if (h < NCH - 1)
      stage_load(imgc + IMG_W1 + (h + 1) * 49152, tid, st);  // W1[h+1]; lands under G2

    // G2: acc += Hs @ W2c (K=64)
    #pragma unroll
    for (int kk = 0; kk < 2; ++kk) {
      int kb = kk * 32 + lkb;
      bf16x8 A[2];
      #pragma unroll
      for (int mt = 0; mt < 2; ++mt) {
        int ra = wr * 32 + mt * 16 + lrow;
        A[mt] = *(const bf16x8*)(lds + L_HS + ((ra * 128 + kb * 2) ^ ((ra & 7) << 4)));
      }
      #pragma unroll
      for (int nt = 0; nt < 6; ++nt) {
        int rb = wc * 96 + nt * 16 + lrow;
        bf16x8 b = *(const bf16x8*)(lds + L_W + ((rb * 128 + kb * 2) ^ ((rb & 7) << 4)));
        #pragma unroll
        for (int mt = 0; mt < 2; ++mt)
          acc[mt][nt] = __builtin_amdgcn_mfma_f32_16x16x32_bf16(A[mt], b, acc[mt][nt], 0, 0, 0);
      }
    }
  }

  // ---- epilogue: + b2 (global), store f32 ----
  #pragma unroll
  for (int nt = 0; nt < 6; ++nt) {
    int col = wc * 96 + nt * 16 + lrow;
    float bb = b2[col];
    #pragma unroll
    for (int mt = 0; mt < 2; ++mt) {
      #pragma unroll
      for (int r = 0; r < 4; ++r) {
        int row = wr * 32 + mt * 16 + g4 * 4 + r;
        out[(size_t)(blockRow + row) * DIM + col] = acc[mt][nt][r] + bb;
      }
    }
  }
}

extern "C" void kernel_launch(void* const* d_in, const int* in_sizes, int n_in,
                              void* d_out, int out_size, void* d_ws, size_t ws_size,
                              hipStream_t stream) {
  const float* x          = (const float*)d_in[0];
  const float* topk_probs = (const float*)d_in[2];
  const int*   topk_idx   = (const int*)  d_in[3];
  const float* w_down     = (const float*)d_in[4];
  const float* w_up       = (const float*)d_in[5];
  const float* W1         = (const float*)d_in[6];
  const float* b1         = (const float*)d_in[7];
  const float* W2         = (const float*)d_in[8];
  const float* b2         = (const float*)d_in[9];
  float* out = (float*)d_out;

  if (ws_size < WS_NEED) return;

  hipFuncSetAttribute(reinterpret_cast<const void*>(fused_k),
                      hipFuncAttributeMaxDynamicSharedMemorySize, LDSZ);

  unsigned short* img = (unsigned short*)d_ws;
  pack_k<<<(NELEMS + 255) / 256, 256, 0, stream>>>(W1, W2, w_down, w_up, img);
  fused_k<<<NBLK, NTH, LDSZ, stream>>>(x, topk_probs, topk_idx, b1, b2, img, out);
}

// Round 8
// 327.335 us; speedup vs baseline: 2.5456x; 2.5456x over previous
//
#include <hip/hip_runtime.h>
#include <hip/hip_bf16.h>

typedef __attribute__((ext_vector_type(4))) float float4v;
typedef __attribute__((ext_vector_type(8))) __bf16 bf16x8;
typedef __attribute__((ext_vector_type(8))) unsigned short ushort8v;

constexpr int NTOK = 50176;
constexpr int DIM  = 384;
constexpr int HID  = 1536;
constexpr int BM   = 64;          // tokens/block
constexpr int NTH  = 512;
constexpr int NBLK = NTOK / BM;   // 784
constexpr int CHW  = 32;          // hidden chunk width
constexpr int NCH  = HID / CHW;   // 48

// workspace (byte offsets) — pre-swizzled bf16 images, 24KB per chunk
constexpr int IMG_WD  = 0;                      // [32 f][384 d] 768B rows
constexpr int IMG_WUP = 24576;                  // [384 d][32 k] 64B rows
constexpr int IMG_W1  = 49152;                  // 48 x [32 f][384 d]
constexpr int IMG_W2  = 49152 + 48 * 24576;     // 48 x [384 d][32 k]
constexpr size_t WS_NEED = 2408448;
constexpr int NELEMS = 1204224;

// LDS byte offsets — 76 KiB => 2 blocks/CU
constexpr int L_X  = 0;        // 48K  X [64][384] bf16, 768B rows, swz (r&7)<<4
constexpr int L_W  = 49152;    // 24K  W chunk buffer (WD/W1c: 768B rows | WUP/W2c: 64B rows)
constexpr int L_HS = 73728;    // 4K   Hs [64][32] bf16, 64B rows, swz (r&3)<<4
constexpr int LDSZ = 77824;

__device__ __forceinline__ unsigned short f2bf(float f) {
  __hip_bfloat16 h = __float2bfloat16(f);
  return *reinterpret_cast<unsigned short*>(&h);
}

__device__ __forceinline__ float gelu_f(float v) {
  float u = 0.7978845608f * (v + 0.044715f * v * v * v);
  float e = __expf(2.0f * u);
  float t = 1.0f - 2.0f / (e + 1.0f);
  return 0.5f * v * (1.0f + t);
}

// 24KB linear copy, transient regs only (recomputable addrs -> remat not spill)
__device__ __forceinline__ void stage3(const char* src, char* dst, int tid) {
  ushort8v t0 = *(const ushort8v*)(src + tid * 16);
  ushort8v t1 = *(const ushort8v*)(src + tid * 16 + 8192);
  ushort8v t2 = *(const ushort8v*)(src + tid * 16 + 16384);
  *(ushort8v*)(dst + tid * 16)         = t0;
  *(ushort8v*)(dst + tid * 16 + 8192)  = t1;
  *(ushort8v*)(dst + tid * 16 + 16384) = t2;
}

// ---------------- pack kernel: f32 weights -> pre-swizzled bf16 images ----------------
__global__ __launch_bounds__(256) void pack_k(
    const float* __restrict__ W1, const float* __restrict__ W2,
    const float* __restrict__ wd, const float* __restrict__ wu,
    unsigned short* __restrict__ img)
{
  int i = blockIdx.x * 256 + threadIdx.x;
  if (i >= NELEMS) return;
  if (i < 12288) {                               // WD: [32 r][384 d] 768B rows, swz (r&7)<<4
    int f = i / 384; int inb = (i % 384) * 2;
    int d = (inb ^ ((f & 7) << 4)) >> 1;
    float v = (f < 24) ? wd[(f >> 3) * (DIM * 8) + d * 8 + (f & 7)] : 0.f;
    img[i] = f2bf(v);
  } else if (i < 24576) {                        // WUP: [384 d][32 k] 64B rows, swz (d&3)<<4
    int j = i - 12288;
    int d = j / 32; int inb = (j % 32) * 2;
    int k = (inb ^ ((d & 3) << 4)) >> 1;
    float v = (k < 24) ? wu[k * DIM + d] : 0.f;
    img[i] = f2bf(v);
  } else if (i < 24576 + 48 * 12288) {           // W1 chunks: [32 f][384 d] 768B rows
    int j = i - 24576; int h = j / 12288; int jc = j % 12288;
    int f = jc / 384; int inb = (jc % 384) * 2;
    int d = (inb ^ ((f & 7) << 4)) >> 1;
    img[i] = f2bf(W1[d * HID + h * CHW + f]);
  } else {                                       // W2 chunks: [384 d][32 k] 64B rows
    int j = i - 24576 - 48 * 12288; int h = j / 12288; int jc = j % 12288;
    int d = jc / 32; int inb = (jc % 32) * 2;
    int k = (inb ^ ((d & 3) << 4)) >> 1;
    img[i] = f2bf(W2[(h * CHW + k) * DIM + d]);
  }
}

// ---------------- fused MLP + MoE-LoRA ----------------
__global__ __launch_bounds__(NTH, 4) void fused_k(
    const float* __restrict__ x,
    const float* __restrict__ tp,
    const int*   __restrict__ ti,
    const float* __restrict__ b1,
    const float* __restrict__ b2,
    const unsigned short* __restrict__ img,
    float* __restrict__ out)
{
  extern __shared__ char lds[];
  const int tid = threadIdx.x, wid = tid >> 6, lane = tid & 63;
  const int lrow = lane & 15, g4 = lane >> 4, lkb = g4 * 8;
  const int blockRow = blockIdx.x * BM;
  const char* imgc = (const char*)img;

  // G1 grid: 4 token-bands x 2 col-halves (16x16 tile per wave)
  const int band = wid >> 1, chh = wid & 1;
  // G2 grid: 2M x 4N (acc[2][6] 16x16 tiles)
  const int wr = wid >> 2, wc = wid & 3;

  // ---- prologue: X f32->bf16 -> L_X (swizzled); WD -> L_W (parallel, disjoint regions) ----
  {
    const float* xb = x + (size_t)blockRow * DIM;
    #pragma unroll
    for (int it = 0; it < 6; ++it) {
      int idx = it * NTH + tid;
      int row = idx / 48, c8 = idx % 48;
      float4v v0 = *(const float4v*)(xb + row * DIM + c8 * 8);
      float4v v1 = *(const float4v*)(xb + row * DIM + c8 * 8 + 4);
      ushort8v u;
      u[0]=f2bf(v0[0]); u[1]=f2bf(v0[1]); u[2]=f2bf(v0[2]); u[3]=f2bf(v0[3]);
      u[4]=f2bf(v1[0]); u[5]=f2bf(v1[1]); u[6]=f2bf(v1[2]); u[7]=f2bf(v1[3]);
      int byte = (row * 768 + c8 * 16) ^ ((row & 7) << 4);
      *(ushort8v*)(lds + L_X + byte) = u;
    }
  }
  stage3(imgc + IMG_WD, lds + L_W, tid);
  __syncthreads();                               // X + WD visible

  // ---- G1-moe: t1 = X @ WdT -> [64][32]; prob*gelu -> Hs ----
  {
    float4v hv = {};
    int raX = band * 16 + lrow, swA = (raX & 7) << 4, baX = raX * 768 + lkb * 2;
    int rbW = chh * 16 + lrow, swB = (rbW & 7) << 4, baW = rbW * 768 + lkb * 2;
    #pragma unroll
    for (int ks = 0; ks < 12; ++ks) {
      bf16x8 a = *(const bf16x8*)(lds + L_X + ((baX + ks * 64) ^ swA));
      bf16x8 b = *(const bf16x8*)(lds + L_W + ((baW + ks * 64) ^ swB));
      hv = __builtin_amdgcn_mfma_f32_16x16x32_bf16(a, b, hv, 0, 0, 0);
    }
    int colc = chh * 16 + lrow; int e = colc >> 3;
    #pragma unroll
    for (int r = 0; r < 4; ++r) {
      int row = band * 16 + g4 * 4 + r;
      int token = blockRow + row;
      float p = 0.f;
      if (e < 3) {
        int i0 = ti[token * 2], i1 = ti[token * 2 + 1];
        if (i0 == e) p += tp[token * 2];
        if (i1 == e) p += tp[token * 2 + 1];
      }
      float gv = p * gelu_f(hv[r]);
      int byte = (row * 64) + ((colc * 2) ^ ((row & 3) << 4));
      *(unsigned short*)(lds + L_HS + byte) = f2bf(gv);
    }
  }
  __syncthreads();                               // Hs visible; L_W (WD) readers done
  stage3(imgc + IMG_WUP, lds + L_W, tid);
  __syncthreads();                               // WUP visible

  // ---- G2-moe: acc = Hs @ WupT (K=32) ----
  float4v acc[2][6] = {};
  {
    bf16x8 A[2];
    #pragma unroll
    for (int mt = 0; mt < 2; ++mt) {
      int ra = wr * 32 + mt * 16 + lrow;
      A[mt] = *(const bf16x8*)(lds + L_HS + ra * 64 + ((g4 * 16) ^ ((ra & 3) << 4)));
    }
    #pragma unroll
    for (int nt = 0; nt < 6; ++nt) {
      int rd = wc * 96 + nt * 16 + lrow;
      bf16x8 b = *(const bf16x8*)(lds + L_W + rd * 64 + ((g4 * 16) ^ ((rd & 3) << 4)));
      acc[0][nt] = __builtin_amdgcn_mfma_f32_16x16x32_bf16(A[0], b, acc[0][nt], 0, 0, 0);
      acc[1][nt] = __builtin_amdgcn_mfma_f32_16x16x32_bf16(A[1], b, acc[1][nt], 0, 0, 0);
    }
  }

  // ---- main loop: 48 chunks of 32 hidden; R4-proven 4-barrier single-buffer ----
  for (int h = 0; h < NCH; ++h) {
    __syncthreads();                             // (a) L_W readers done
    stage3(imgc + IMG_W1 + h * 24576, lds + L_W, tid);
    __syncthreads();                             // (b) W1c visible

    // G1: H = X @ W1c -> [64][32]
    float4v hv = {};
    {
      int raX = band * 16 + lrow, swA = (raX & 7) << 4, baX = raX * 768 + lkb * 2;
      int rbW = chh * 16 + lrow, swB = (rbW & 7) << 4, baW = rbW * 768 + lkb * 2;
      #pragma unroll
      for (int ks = 0; ks < 12; ++ks) {
        bf16x8 a = *(const bf16x8*)(lds + L_X + ((baX + ks * 64) ^ swA));
        bf16x8 b = *(const bf16x8*)(lds + L_W + ((baW + ks * 64) ^ swB));
        hv = __builtin_amdgcn_mfma_f32_16x16x32_bf16(a, b, hv, 0, 0, 0);
      }
    }
    // bias + gelu -> Hs
    {
      int colc = chh * 16 + lrow;
      float bb = b1[h * CHW + colc];
      #pragma unroll
      for (int r = 0; r < 4; ++r) {
        int row = band * 16 + g4 * 4 + r;
        float gv = gelu_f(hv[r] + bb);
        int byte = (row * 64) + ((colc * 2) ^ ((row & 3) << 4));
        *(unsigned short*)(lds + L_HS + byte) = f2bf(gv);
      }
    }
    __syncthreads();                             // (c) Hs visible; G1's L_W reads done
    stage3(imgc + IMG_W2 + h * 24576, lds + L_W, tid);
    __syncthreads();                             // (d) W2c visible

    // G2: acc += Hs @ W2c (K=32)
    {
      bf16x8 A[2];
      #pragma unroll
      for (int mt = 0; mt < 2; ++mt) {
        int ra = wr * 32 + mt * 16 + lrow;
        A[mt] = *(const bf16x8*)(lds + L_HS + ra * 64 + ((g4 * 16) ^ ((ra & 3) << 4)));
      }
      #pragma unroll
      for (int nt = 0; nt < 6; ++nt) {
        int rd = wc * 96 + nt * 16 + lrow;
        bf16x8 b = *(const bf16x8*)(lds + L_W + rd * 64 + ((g4 * 16) ^ ((rd & 3) << 4)));
        acc[0][nt] = __builtin_amdgcn_mfma_f32_16x16x32_bf16(A[0], b, acc[0][nt], 0, 0, 0);
        acc[1][nt] = __builtin_amdgcn_mfma_f32_16x16x32_bf16(A[1], b, acc[1][nt], 0, 0, 0);
      }
    }
  }

  // ---- epilogue: + b2, store f32 ----
  #pragma unroll
  for (int nt = 0; nt < 6; ++nt) {
    int col = wc * 96 + nt * 16 + lrow;
    float bb = b2[col];
    #pragma unroll
    for (int mt = 0; mt < 2; ++mt) {
      #pragma unroll
      for (int r = 0; r < 4; ++r) {
        int row = wr * 32 + mt * 16 + g4 * 4 + r;
        out[(size_t)(blockRow + row) * DIM + col] = acc[mt][nt][r] + bb;
      }
    }
  }
}

extern "C" void kernel_launch(void* const* d_in, const int* in_sizes, int n_in,
                              void* d_out, int out_size, void* d_ws, size_t ws_size,
                              hipStream_t stream) {
  const float* x          = (const float*)d_in[0];
  const float* topk_probs = (const float*)d_in[2];
  const int*   topk_idx   = (const int*)  d_in[3];
  const float* w_down     = (const float*)d_in[4];
  const float* w_up       = (const float*)d_in[5];
  const float* W1         = (const float*)d_in[6];
  const float* b1         = (const float*)d_in[7];
  const float* W2         = (const float*)d_in[8];
  const float* b2         = (const float*)d_in[9];
  float* out = (float*)d_out;

  if (ws_size < WS_NEED) return;

  hipFuncSetAttribute(reinterpret_cast<const void*>(fused_k),
                      hipFuncAttributeMaxDynamicSharedMemorySize, LDSZ);

  unsigned short* img = (unsigned short*)d_ws;
  pack_k<<<(NELEMS + 255) / 256, 256, 0, stream>>>(W1, W2, w_down, w_up, img);
  fused_k<<<NBLK, NTH, LDSZ, stream>>>(x, topk_probs, topk_idx, b1, b2, img, out);
}